// Round 15
// baseline (580.194 us; speedup 1.0000x reference)
//
#include <hip/hip_runtime.h>
#include <math.h>

#define MAX_K 32
#define CUTOFF 5.0f

// Sign map (resolved R1-R6): canonical(max-component-positive) -> LAPACK.
#define SIGN0 -1.0f
#define SIGN1 -1.0f
#define SIGN2 -1.0f

// ---------------- fast path: counting-sort by atom ----------------

// fused: per-edge r (coalesced write; aliases F buffer) + atom histogram
__global__ __launch_bounds__(256) void r_hist_kernel(const float* __restrict__ vec,
                                                     const int* __restrict__ atom,
                                                     float* __restrict__ r_all,
                                                     int* __restrict__ count, int E) {
  int e = blockIdx.x * blockDim.x + threadIdx.x;
  if (e >= E) return;
  float x = vec[3 * e + 0], y = vec[3 * e + 1], z = vec[3 * e + 2];
  r_all[e] = sqrtf(x * x + y * y + z * z) * (1.0f / CUTOFF);
  atomicAdd(&count[atom[e]], 1);
}

// coalesced scan, pass A: per-block (1024-wide) sums
__global__ __launch_bounds__(1024) void bsum_kernel(const int* __restrict__ count,
                                                    int* __restrict__ bsum, int n) {
  __shared__ int red[1024];
  int t = threadIdx.x;
  int i = blockIdx.x * 1024 + t;
  red[t] = (i < n) ? count[i] : 0;
  __syncthreads();
  for (int d = 512; d > 0; d >>= 1) {
    if (t < d) red[t] += red[t + d];
    __syncthreads();
  }
  if (t == 0) bsum[blockIdx.x] = red[0];
}

// pass B: exclusive scan of block sums (nb <= 1024), in LDS
__global__ __launch_bounds__(1024) void bscan_kernel(const int* __restrict__ bsum,
                                                     int* __restrict__ bbase, int nb) {
  __shared__ int v[1024];
  int t = threadIdx.x;
  v[t] = (t < nb) ? bsum[t] : 0;
  __syncthreads();
  if (t == 0) {
    int run = 0;
    for (int i = 0; i < nb; ++i) { int c = v[i]; v[i] = run; run += c; }
  }
  __syncthreads();
  if (t < nb) bbase[t] = v[t];
}

// pass C: in-block Hillis-Steele scan + block base; coalesced offset/cursor
__global__ __launch_bounds__(1024) void apply_kernel(const int* __restrict__ count,
                                                     const int* __restrict__ bbase,
                                                     int* __restrict__ offset,
                                                     int* __restrict__ cursor, int n) {
  __shared__ int part[1024];
  int t = threadIdx.x;
  int i = blockIdx.x * 1024 + t;
  int x = (i < n) ? count[i] : 0;
  part[t] = x;
  __syncthreads();
  for (int d = 1; d < 1024; d <<= 1) {
    int add = (t >= d) ? part[t - d] : 0;
    __syncthreads();
    part[t] += add;
    __syncthreads();
  }
  int excl = part[t] - x + bbase[blockIdx.x];
  if (i < n) { offset[i] = excl; cursor[i] = excl; }
}

// XCD-range-partitioned scatter (R13 win): group g = blockIdx%8 owns atoms
// [g*n/8,(g+1)*n/8); per-group write region 1.6MB stays in that XCD's L2.
__global__ __launch_bounds__(256) void scatter8_kernel(const float* __restrict__ r_all,
                                                       const int* __restrict__ atom,
                                                       int* __restrict__ cursor,
                                                       float* __restrict__ sr,
                                                       int E, int n_atoms, int nbpg) {
  int g = blockIdx.x & 7;
  int cb = blockIdx.x >> 3;
  int lo = (int)(((long long)g * n_atoms) >> 3);
  int hi = (int)(((long long)(g + 1) * n_atoms) >> 3);
  int stride = nbpg * 256;
  for (int e = cb * 256 + threadIdx.x; e < E; e += stride) {
    int a = atom[e];
    if (a >= lo && a < hi) {
      int pos = atomicAdd(&cursor[a], 1);
      sr[pos] = r_all[e];
    }
  }
}

// fused build+gram: per-atom acc[32] in registers -> padded LDS rows ->
// per-block pair-sum reduction -> f64 atomics into G,S. F never materialized.
__global__ __launch_bounds__(256) void buildgram_kernel(const float* __restrict__ sr,
                                                        const int* __restrict__ offset,
                                                        const int* __restrict__ count,
                                                        double* __restrict__ G,
                                                        double* __restrict__ S, int n) {
  __shared__ float rows[256][MAX_K + 1];  // +1 pad: conflict-free col writes
  int tid = threadIdx.x;
  int a = blockIdx.x * 256 + tid;
  float acc[MAX_K];
#pragma unroll
  for (int k = 0; k < MAX_K; ++k) acc[k] = 0.f;
  if (a < n) {
    int o = offset[a], c = count[a];
    for (int i = 0; i < c; ++i) {
      float r = sr[o + i];
      float p = 1.f;
#pragma unroll
      for (int k = 0; k < MAX_K; ++k) { acc[k] += p; p *= r; }
    }
  }
#pragma unroll
  for (int k = 0; k < MAX_K; ++k) rows[tid][k] = acc[k];
  __syncthreads();

  // 528 unique (i<=j) pairs; thread handles <=3
  int pi[3], pj[3];
  int npair = 0;
  for (int p = tid; p < 528; p += 256) {
    int i = 0, pp = p;
    while (pp >= MAX_K - i) { pp -= (MAX_K - i); i++; }
    pi[npair] = i;
    pj[npair] = i + pp;
    npair++;
  }
  double accp[3] = {0.0, 0.0, 0.0};
  double colsum = 0.0;
  for (int r = 0; r < 256; ++r) {
    for (int t = 0; t < npair; ++t)
      accp[t] += (double)rows[r][pi[t]] * (double)rows[r][pj[t]];
    if (tid < MAX_K) colsum += (double)rows[r][tid];
  }
  for (int t = 0; t < npair; ++t) atomicAdd(&G[pi[t] * MAX_K + pj[t]], accp[t]);
  if (tid < MAX_K) atomicAdd(&S[tid], colsum);
}

// proj with recompute: per-atom powers from sr, dot with V3 rows
__global__ __launch_bounds__(256) void projr_kernel(const float* __restrict__ sr,
                                                    const int* __restrict__ offset,
                                                    const int* __restrict__ count,
                                                    const float* __restrict__ V3,
                                                    float* __restrict__ out, int n) {
  __shared__ float v[96];
  if (threadIdx.x < 96) v[threadIdx.x] = V3[threadIdx.x];
  __syncthreads();
  int a = blockIdx.x * 256 + threadIdx.x;
  if (a >= n) return;
  int o = offset[a], c = count[a];
  float s0 = 0.f, s1 = 0.f, s2 = 0.f;
  for (int i = 0; i < c; ++i) {
    float r = sr[o + i];
    float p = 1.f;
#pragma unroll
    for (int k = 0; k < MAX_K; ++k) {
      s0 += p * v[k];
      s1 += p * v[32 + k];
      s2 += p * v[64 + k];
      p *= r;
    }
  }
  out[3 * a + 0] = s0;
  out[3 * a + 1] = s1;
  out[3 * a + 2] = s2;
}

// ---------------- fallback path (small ws): direct atomics ----------------
__global__ __launch_bounds__(256) void edge_kernel(const float* __restrict__ vec,
                                                   const int* __restrict__ atom,
                                                   float* __restrict__ F, int E) {
  int e = blockIdx.x * blockDim.x + threadIdx.x;
  if (e >= E) return;
  float x = vec[3 * e + 0], y = vec[3 * e + 1], z = vec[3 * e + 2];
  float r = sqrtf(x * x + y * y + z * z) * (1.0f / CUTOFF);
  float* out = F + (size_t)atom[e] * MAX_K;
  float p = 1.0f;
#pragma unroll
  for (int k = 0; k < MAX_K; ++k) {
    atomicAdd(out + k, p);
    p *= r;
  }
}

// fallback gram (reads F)
__global__ __launch_bounds__(256) void gram_kernel(const float* __restrict__ F, int n,
                                                   double* __restrict__ G,
                                                   double* __restrict__ S) {
  __shared__ float rows[8][MAX_K];
  int tid = threadIdx.x;
  int pi[3], pj[3];
  int npair = 0;
  for (int p = tid; p < 528; p += 256) {
    int i = 0, pp = p;
    while (pp >= MAX_K - i) { pp -= (MAX_K - i); i++; }
    pi[npair] = i;
    pj[npair] = i + pp;
    npair++;
  }
  double acc[3] = {0.0, 0.0, 0.0};
  double colsum = 0.0;
  int nchunk = (n + 7) / 8;
  int row = tid >> 5, col = tid & 31;
  for (int ch = blockIdx.x; ch < nchunk; ch += gridDim.x) {
    int a = ch * 8 + row;
    rows[row][col] = (a < n) ? F[(size_t)a * MAX_K + col] : 0.0f;
    __syncthreads();
#pragma unroll
    for (int r = 0; r < 8; ++r) {
      for (int t = 0; t < npair; ++t)
        acc[t] += (double)rows[r][pi[t]] * (double)rows[r][pj[t]];
      if (tid < MAX_K) colsum += (double)rows[r][tid];
    }
    __syncthreads();
  }
  for (int t = 0; t < npair; ++t) atomicAdd(&G[pi[t] * MAX_K + pj[t]], acc[t]);
  if (tid < MAX_K) atomicAdd(&S[tid], colsum);
}

// fallback proj (reads F)
__global__ __launch_bounds__(256) void proj_kernel(const float* __restrict__ F,
                                                   const float* __restrict__ V3,
                                                   float* __restrict__ out, int n) {
  __shared__ float v[96];
  if (threadIdx.x < 96) v[threadIdx.x] = V3[threadIdx.x];
  __syncthreads();
  int a = blockIdx.x * blockDim.x + threadIdx.x;
  if (a >= n) return;
  const float4* rowp = (const float4*)(F + (size_t)a * 32);
  float s0 = 0.f, s1 = 0.f, s2 = 0.f;
#pragma unroll
  for (int k4 = 0; k4 < 8; ++k4) {
    float4 f = rowp[k4];
    int k = k4 * 4;
    s0 += f.x * v[k] + f.y * v[k + 1] + f.z * v[k + 2] + f.w * v[k + 3];
    s1 += f.x * v[32 + k] + f.y * v[32 + k + 1] + f.z * v[32 + k + 2] + f.w * v[32 + k + 3];
    s2 += f.x * v[64 + k] + f.y * v[64 + k + 1] + f.z * v[64 + k + 2] + f.w * v[64 + k + 3];
  }
  out[3 * a + 0] = s0;
  out[3 * a + 1] = s1;
  out[3 * a + 2] = s2;
}

// Pass 3 (1 block = 4 waves, 256 thr): centered Gram, parallel Jacobi.
// A f64, V f32. ALL threads compute rotation params for their own pairs
// (redundant, parallel; bit-identical c,s) — removes the 16-lane serial
// phase-0 + LDS broadcast of R14. 3 barriers/round.
__global__ __launch_bounds__(256) void eig_kernel(const double* __restrict__ Gin,
                                                  const double* __restrict__ S,
                                                  float* __restrict__ V3, int n_atoms) {
  __shared__ double A[32][33];
  __shared__ float V[32][33];
  __shared__ double wred[4];
  __shared__ int sel[3];
  __shared__ double ssign[3];
  int t = threadIdx.x;
  int lane = t & 31;   // col (phase 1) / row (phase 2)
  int w = t >> 5;      // 0..7: item slots k = w + 8*i, i=0..1

  double stot = 0.0;
  for (int k = 0; k < 32; ++k) stot += S[k];
  double mu = stot / ((double)n_atoms * 32.0);

  for (int idx = t; idx < 1024; idx += 256) {
    int i = idx >> 5, j = idx & 31;
    double g = (i <= j) ? Gin[i * 32 + j] : Gin[j * 32 + i];
    A[i][j] = g - mu * (S[i] + S[j]) + mu * mu * (double)n_atoms;
    V[i][j] = (i == j) ? 1.0f : 0.0f;
  }
  __syncthreads();

  double part = 0.0;
  for (int idx = t; idx < 1024; idx += 256) {
    int i = idx >> 5, j = idx & 31;
    part += A[i][j] * A[i][j];
  }
  for (int o = 32; o; o >>= 1) part += __shfl_xor(part, o, 64);
  if ((t & 63) == 0) wred[t >> 6] = part;
  __syncthreads();
  double fro2 = wred[0] + wred[1] + wred[2] + wred[3];
  double skip_thr = 1e-14 * sqrt(fro2);
  double off_tol2 = fro2 * 3e-13;
  __syncthreads();

  int q0 = 0;
  int ak[2], bk[2];
#pragma unroll
  for (int i = 0; i < 2; ++i) {
    int k = w + 8 * i;
    ak[i] = k;                    // k <= 15 < 31
    bk[i] = (k == 0) ? 0 : (31 - k);
  }

  for (int sweep = 0; sweep < 8; ++sweep) {
    double off = 0.0;
    for (int idx = t; idx < 1024; idx += 256) {
      int i = idx >> 5, j = idx & 31;
      if (i != j) off += A[i][j] * A[i][j];
    }
    for (int o = 32; o; o >>= 1) off += __shfl_xor(off, o, 64);
    if ((t & 63) == 0) wred[t >> 6] = off;
    __syncthreads();
    double offT = wred[0] + wred[1] + wred[2] + wred[3];
    __syncthreads();
    if (offT <= off_tol2) break;

    for (int r = 0; r < 31; ++r) {
      // params: every thread computes (c,s) for its own 2 pairs (reads only)
      int pk[2], qk[2];
      float ck[2], sk[2];
#pragma unroll
      for (int i = 0; i < 2; ++i) {
        int k = w + 8 * i;
        if (k == 0) { pk[i] = 31; qk[i] = q0; }
        else {
          pk[i] = (ak[i] < bk[i]) ? ak[i] : bk[i];
          qk[i] = (ak[i] < bk[i]) ? bk[i] : ak[i];
        }
        double apq = A[pk[i]][qk[i]];
        float cf = 1.0f, sf = 0.0f;
        if (fabs(apq) > skip_thr) {
          double app = A[pk[i]][pk[i]], aqq = A[qk[i]][qk[i]];
          float tau = (float)(aqq - app) / (float)(2.0 * apq);
          float tt = 1.0f / (fabsf(tau) + sqrtf(1.0f + tau * tau));
          if (tau < 0.0f) tt = -tt;
          cf = 1.0f / sqrtf(1.0f + tt * tt);
          sf = tt * cf;
        }
        ck[i] = cf; sk[i] = sf;
      }
      __syncthreads();  // B1: all param reads complete before phase-1 writes

      // phase 1: row update A <- J^T A (col = lane); 2 disjoint pairs/thread
      double ap[2], aq[2];
#pragma unroll
      for (int i = 0; i < 2; ++i) { ap[i] = A[pk[i]][lane]; aq[i] = A[qk[i]][lane]; }
#pragma unroll
      for (int i = 0; i < 2; ++i) {
        double c = (double)ck[i], s = (double)sk[i];
        A[pk[i]][lane] = c * ap[i] - s * aq[i];
        A[qk[i]][lane] = s * ap[i] + c * aq[i];
      }
      __syncthreads();  // B2
      // phase 2: col update A <- A J (f64), V <- V J (f32)
      double bp[2], bq[2];
      float vp[2], vq[2];
#pragma unroll
      for (int i = 0; i < 2; ++i) { bp[i] = A[lane][pk[i]]; bq[i] = A[lane][qk[i]]; }
#pragma unroll
      for (int i = 0; i < 2; ++i) { vp[i] = V[lane][pk[i]]; vq[i] = V[lane][qk[i]]; }
#pragma unroll
      for (int i = 0; i < 2; ++i) {
        double c = (double)ck[i], s = (double)sk[i];
        A[lane][pk[i]] = c * bp[i] - s * bq[i];
        A[lane][qk[i]] = s * bp[i] + c * bq[i];
        V[lane][pk[i]] = ck[i] * vp[i] - sk[i] * vq[i];
        V[lane][qk[i]] = sk[i] * vp[i] + ck[i] * vq[i];
      }
      __syncthreads();  // B3
#pragma unroll
      for (int i = 0; i < 2; ++i) {
        ak[i] = (ak[i] == 30) ? 0 : ak[i] + 1;
        bk[i] = (bk[i] == 30) ? 0 : bk[i] + 1;
      }
      q0 = (q0 == 30) ? 0 : q0 + 1;
    }
  }
  __syncthreads();

  if (t == 0) {
    bool used[32];
    for (int i = 0; i < 32; ++i) used[i] = false;
    for (int j = 0; j < 3; ++j) {
      int best = 0; double bv = -1e300;
      for (int i = 0; i < 32; ++i)
        if (!used[i] && A[i][i] > bv) { bv = A[i][i]; best = i; }
      used[best] = true;
      sel[j] = best;
      int m = 0; float mv = fabsf(V[0][best]);
      for (int i = 1; i < 32; ++i) {
        float av = fabsf(V[i][best]);
        if (av > mv) { mv = av; m = i; }
      }
      ssign[j] = (V[m][best] < 0.0f) ? -1.0 : 1.0;
    }
  }
  __syncthreads();
  const float adj[3] = {SIGN0, SIGN1, SIGN2};
  if (t < 32) {
    for (int j = 0; j < 3; ++j)
      V3[j * 32 + t] = (float)ssign[j] * V[t][sel[j]] * adj[j];
  }
}

extern "C" void kernel_launch(void* const* d_in, const int* in_sizes, int n_in,
                              void* d_out, int out_size, void* d_ws, size_t ws_size,
                              hipStream_t stream) {
  const float* vec = (const float*)d_in[0];
  const int* atom = (const int*)d_in[1];
  int E = in_sizes[1];
  int n_atoms = out_size / 3;
  int nb = (n_atoms + 1023) >> 10;  // blocks for the coalesced scan (<=1024)

  char* ws = (char*)d_ws;
  auto nalign = [](size_t x) { return (x + 255) & ~(size_t)255; };

  size_t F_bytes = (size_t)n_atoms * MAX_K * sizeof(float);
  size_t sr_bytes = (size_t)E * sizeof(float);
  size_t i_bytes = (size_t)n_atoms * sizeof(int);

  size_t F_off = 0;
  size_t sr_off = nalign(F_off + F_bytes);
  size_t offs_off = nalign(sr_off + sr_bytes);
  size_t cur_off = nalign(offs_off + i_bytes);
  size_t cnt_off = nalign(cur_off + i_bytes);
  size_t G_off = nalign(cnt_off + i_bytes);
  size_t S_off = nalign(G_off + 1024 * sizeof(double));
  size_t bs_off = nalign(S_off + 32 * sizeof(double));
  size_t bb_off = nalign(bs_off + 1024 * sizeof(int));
  size_t V3_off = nalign(bb_off + 1024 * sizeof(int));
  size_t total = nalign(V3_off + 96 * sizeof(float));

  float* F = (float*)(ws + F_off);
  double* G = (double*)(ws + G_off);
  double* S = (double*)(ws + S_off);
  float* V3 = (float*)(ws + V3_off);

  // r_all aliases F's buffer (E*4B == n_atoms*32*4B); fast path never
  // materializes F — buffer serves as r_all only.
  float* r_all = F;

  if (ws_size >= total && sr_bytes <= F_bytes) {
    float* sr = (float*)(ws + sr_off);
    int* offset = (int*)(ws + offs_off);
    int* cursor = (int*)(ws + cur_off);
    int* count = (int*)(ws + cnt_off);
    int* bsum = (int*)(ws + bs_off);
    int* bbase = (int*)(ws + bb_off);
    // zero count + G + S (contiguous region)
    hipMemsetAsync(ws + cnt_off, 0, S_off + 32 * sizeof(double) - cnt_off, stream);
    r_hist_kernel<<<(E + 255) / 256, 256, 0, stream>>>(vec, atom, r_all, count, E);
    bsum_kernel<<<nb, 1024, 0, stream>>>(count, bsum, n_atoms);
    bscan_kernel<<<1, 1024, 0, stream>>>(bsum, bbase, nb);
    apply_kernel<<<nb, 1024, 0, stream>>>(count, bbase, offset, cursor, n_atoms);
    int nbpg = 512;  // blocks per group; grid = 8 * nbpg
    scatter8_kernel<<<8 * nbpg, 256, 0, stream>>>(r_all, atom, cursor, sr, E, n_atoms, nbpg);
    buildgram_kernel<<<(n_atoms + 255) / 256, 256, 0, stream>>>(sr, offset, count, G, S, n_atoms);
    eig_kernel<<<1, 256, 0, stream>>>(G, S, V3, n_atoms);
    projr_kernel<<<(n_atoms + 255) / 256, 256, 0, stream>>>(sr, offset, count, V3, (float*)d_out, n_atoms);
  } else {
    hipMemsetAsync(ws, 0, F_bytes, stream);
    hipMemsetAsync(ws + cnt_off, 0, S_off + 32 * sizeof(double) - cnt_off, stream);
    edge_kernel<<<(E + 255) / 256, 256, 0, stream>>>(vec, atom, F, E);
    gram_kernel<<<1024, 256, 0, stream>>>(F, n_atoms, G, S);
    eig_kernel<<<1, 256, 0, stream>>>(G, S, V3, n_atoms);
    proj_kernel<<<(n_atoms + 255) / 256, 256, 0, stream>>>(F, V3, (float*)d_out, n_atoms);
  }
}

// Round 16
// 497.800 us; speedup vs baseline: 1.1655x; 1.1655x over previous
//
#include <hip/hip_runtime.h>
#include <math.h>

#define MAX_K 32
#define CUTOFF 5.0f

// Sign map (resolved R1-R6): canonical(max-component-positive) -> LAPACK.
#define SIGN0 -1.0f
#define SIGN1 -1.0f
#define SIGN2 -1.0f

// ---------------- fast path: counting-sort by atom ----------------

// fused: per-edge r (coalesced write; aliases F buffer) + atom histogram
__global__ __launch_bounds__(256) void r_hist_kernel(const float* __restrict__ vec,
                                                     const int* __restrict__ atom,
                                                     float* __restrict__ r_all,
                                                     int* __restrict__ count, int E) {
  int e = blockIdx.x * blockDim.x + threadIdx.x;
  if (e >= E) return;
  float x = vec[3 * e + 0], y = vec[3 * e + 1], z = vec[3 * e + 2];
  r_all[e] = sqrtf(x * x + y * y + z * z) * (1.0f / CUTOFF);
  atomicAdd(&count[atom[e]], 1);
}

// coalesced scan, pass A: per-block (1024-wide) sums
__global__ __launch_bounds__(1024) void bsum_kernel(const int* __restrict__ count,
                                                    int* __restrict__ bsum, int n) {
  __shared__ int red[1024];
  int t = threadIdx.x;
  int i = blockIdx.x * 1024 + t;
  red[t] = (i < n) ? count[i] : 0;
  __syncthreads();
  for (int d = 512; d > 0; d >>= 1) {
    if (t < d) red[t] += red[t + d];
    __syncthreads();
  }
  if (t == 0) bsum[blockIdx.x] = red[0];
}

// pass B: exclusive scan of block sums (nb <= 1024), in LDS
__global__ __launch_bounds__(1024) void bscan_kernel(const int* __restrict__ bsum,
                                                     int* __restrict__ bbase, int nb) {
  __shared__ int v[1024];
  int t = threadIdx.x;
  v[t] = (t < nb) ? bsum[t] : 0;
  __syncthreads();
  if (t == 0) {
    int run = 0;
    for (int i = 0; i < nb; ++i) { int c = v[i]; v[i] = run; run += c; }
  }
  __syncthreads();
  if (t < nb) bbase[t] = v[t];
}

// pass C: in-block Hillis-Steele scan + block base; coalesced offset/cursor
__global__ __launch_bounds__(1024) void apply_kernel(const int* __restrict__ count,
                                                     const int* __restrict__ bbase,
                                                     int* __restrict__ offset,
                                                     int* __restrict__ cursor, int n) {
  __shared__ int part[1024];
  int t = threadIdx.x;
  int i = blockIdx.x * 1024 + t;
  int x = (i < n) ? count[i] : 0;
  part[t] = x;
  __syncthreads();
  for (int d = 1; d < 1024; d <<= 1) {
    int add = (t >= d) ? part[t - d] : 0;
    __syncthreads();
    part[t] += add;
    __syncthreads();
  }
  int excl = part[t] - x + bbase[blockIdx.x];
  if (i < n) { offset[i] = excl; cursor[i] = excl; }
}

// XCD-range-partitioned scatter (R13 win): group g = blockIdx%8 owns atoms
// [g*n/8,(g+1)*n/8); per-group write region 1.6MB stays in that XCD's L2.
__global__ __launch_bounds__(256) void scatter8_kernel(const float* __restrict__ r_all,
                                                       const int* __restrict__ atom,
                                                       int* __restrict__ cursor,
                                                       float* __restrict__ sr,
                                                       int E, int n_atoms, int nbpg) {
  int g = blockIdx.x & 7;
  int cb = blockIdx.x >> 3;
  int lo = (int)(((long long)g * n_atoms) >> 3);
  int hi = (int)(((long long)(g + 1) * n_atoms) >> 3);
  int stride = nbpg * 256;
  for (int e = cb * 256 + threadIdx.x; e < E; e += stride) {
    int a = atom[e];
    if (a >= lo && a < hi) {
      int pos = atomicAdd(&cursor[a], 1);
      sr[pos] = r_all[e];
    }
  }
}

// build: per-atom register accumulation of all 32 powers; coalesced F write.
// (R15 lesson: keep F materialized — recompute in proj costs more than the
// cheap L2-streaming F reads it saves.)
__global__ __launch_bounds__(256) void build_kernel(const float* __restrict__ sr,
                                                    const int* __restrict__ offset,
                                                    const int* __restrict__ count,
                                                    float* __restrict__ F, int n) {
  int a = blockIdx.x * blockDim.x + threadIdx.x;
  if (a >= n) return;
  float acc[MAX_K];
#pragma unroll
  for (int k = 0; k < MAX_K; ++k) acc[k] = 0.f;
  int o = offset[a], c = count[a];
  for (int i = 0; i < c; ++i) {
    float r = sr[o + i];
    float p = 1.f;
#pragma unroll
    for (int k = 0; k < MAX_K; ++k) { acc[k] += p; p *= r; }
  }
  float4* out = (float4*)(F + (size_t)a * MAX_K);
#pragma unroll
  for (int k4 = 0; k4 < 8; ++k4)
    out[k4] = make_float4(acc[4 * k4], acc[4 * k4 + 1], acc[4 * k4 + 2], acc[4 * k4 + 3]);
}

// ---------------- fallback path (small ws): direct atomics ----------------
__global__ __launch_bounds__(256) void edge_kernel(const float* __restrict__ vec,
                                                   const int* __restrict__ atom,
                                                   float* __restrict__ F, int E) {
  int e = blockIdx.x * blockDim.x + threadIdx.x;
  if (e >= E) return;
  float x = vec[3 * e + 0], y = vec[3 * e + 1], z = vec[3 * e + 2];
  float r = sqrtf(x * x + y * y + z * z) * (1.0f / CUTOFF);
  float* out = F + (size_t)atom[e] * MAX_K;
  float p = 1.0f;
#pragma unroll
  for (int k = 0; k < MAX_K; ++k) {
    atomicAdd(out + k, p);
    p *= r;
  }
}

// Pass 2: G = F^T F (upper triangle) and column sums S, accumulated in f64.
__global__ __launch_bounds__(256) void gram_kernel(const float* __restrict__ F, int n,
                                                   double* __restrict__ G,
                                                   double* __restrict__ S) {
  __shared__ float rows[8][MAX_K];
  int tid = threadIdx.x;
  int pi[3], pj[3];
  int npair = 0;
  for (int p = tid; p < 528; p += 256) {
    int i = 0, pp = p;
    while (pp >= MAX_K - i) { pp -= (MAX_K - i); i++; }
    pi[npair] = i;
    pj[npair] = i + pp;
    npair++;
  }
  double acc[3] = {0.0, 0.0, 0.0};
  double colsum = 0.0;
  int nchunk = (n + 7) / 8;
  int row = tid >> 5, col = tid & 31;
  for (int ch = blockIdx.x; ch < nchunk; ch += gridDim.x) {
    int a = ch * 8 + row;
    rows[row][col] = (a < n) ? F[(size_t)a * MAX_K + col] : 0.0f;
    __syncthreads();
#pragma unroll
    for (int r = 0; r < 8; ++r) {
      for (int t = 0; t < npair; ++t)
        acc[t] += (double)rows[r][pi[t]] * (double)rows[r][pj[t]];
      if (tid < MAX_K) colsum += (double)rows[r][tid];
    }
    __syncthreads();
  }
  for (int t = 0; t < npair; ++t) atomicAdd(&G[pi[t] * MAX_K + pj[t]], acc[t]);
  if (tid < MAX_K) atomicAdd(&S[tid], colsum);
}

// Pass 3 (1 block = 4 waves, 256 thr): centered Gram, parallel Jacobi,
// 2x2-BLOCK UPDATE: the 16 disjoint pairs partition {0..31}, so element
// (i,j) belongs to exactly one (row-pair ki, col-pair kj). Thread (ki,kj)
// owns its 2x2 block: read 4 elems, row-rotate (ki) then col-rotate (kj)
// in registers, write back. No intra-update hazard -> 2 barriers/round,
// A LDS traffic halved vs separate row/col phases (R14).
// A f64, V f32; params by 16 lanes in f32 (R14-proven form).
__global__ __launch_bounds__(256) void eig_kernel(const double* __restrict__ Gin,
                                                  const double* __restrict__ S,
                                                  float* __restrict__ V3, int n_atoms) {
  __shared__ double A[32][33];
  __shared__ float V[32][33];
  __shared__ float rcs[16], rss[16];
  __shared__ double wred[4];
  __shared__ int sel[3];
  __shared__ double ssign[3];
  int t = threadIdx.x;
  int ki = t >> 4;   // row-pair slot
  int kj = t & 15;   // col-pair slot

  double stot = 0.0;
  for (int k = 0; k < 32; ++k) stot += S[k];
  double mu = stot / ((double)n_atoms * 32.0);

  for (int idx = t; idx < 1024; idx += 256) {
    int i = idx >> 5, j = idx & 31;
    double g = (i <= j) ? Gin[i * 32 + j] : Gin[j * 32 + i];
    A[i][j] = g - mu * (S[i] + S[j]) + mu * mu * (double)n_atoms;
    V[i][j] = (i == j) ? 1.0f : 0.0f;
  }
  __syncthreads();

  double part = 0.0;
  for (int idx = t; idx < 1024; idx += 256) {
    int i = idx >> 5, j = idx & 31;
    part += A[i][j] * A[i][j];
  }
  for (int o = 32; o; o >>= 1) part += __shfl_xor(part, o, 64);
  if ((t & 63) == 0) wred[t >> 6] = part;
  __syncthreads();
  double fro2 = wred[0] + wred[1] + wred[2] + wred[3];
  double skip_thr = 1e-14 * sqrt(fro2);
  double off_tol2 = fro2 * 3e-13;  // just above f32-param off-norm floor
  __syncthreads();

  // round-robin pair state (mod-31 incremental; slot 0 pairs 31 with q0)
  int q0 = 0;
  int ai_ = ki, bi_ = (ki == 0) ? 0 : (31 - ki);
  int aj_ = kj, bj_ = (kj == 0) ? 0 : (31 - kj);
  int ma = (t < 16) ? t : 0;               // param-thread slot state
  int mb = (t >= 1 && t < 16) ? (31 - t) : 0;

  for (int sweep = 0; sweep < 8; ++sweep) {
    double off = 0.0;
    for (int idx = t; idx < 1024; idx += 256) {
      int i = idx >> 5, j = idx & 31;
      if (i != j) off += A[i][j] * A[i][j];
    }
    for (int o = 32; o; o >>= 1) off += __shfl_xor(off, o, 64);
    if ((t & 63) == 0) wred[t >> 6] = off;
    __syncthreads();
    double offT = wred[0] + wred[1] + wred[2] + wred[3];
    __syncthreads();
    if (offT <= off_tol2) break;

    for (int r = 0; r < 31; ++r) {
      // P: 16 lanes compute f32 (c,s) -> LDS broadcast
      if (t < 16) {
        float cf = 1.0f, sf = 0.0f;
        int p, q;
        if (t == 0) { p = 31; q = q0; }
        else { p = (ma < mb) ? ma : mb; q = (ma < mb) ? mb : ma; }
        double apq = A[p][q];
        if (fabs(apq) > skip_thr) {
          double app = A[p][p], aqq = A[q][q];
          float tau = (float)(aqq - app) / (float)(2.0 * apq);
          float tt = 1.0f / (fabsf(tau) + sqrtf(1.0f + tau * tau));
          if (tau < 0.0f) tt = -tt;
          cf = 1.0f / sqrtf(1.0f + tt * tt);
          sf = tt * cf;
        }
        rcs[t] = cf; rss[t] = sf;
      }
      __syncthreads();  // B1: params visible; prior-round writes fenced

      // U: 2x2 block update (each element owned by exactly one thread)
      int pi_, qi_, pj_, qj_;
      if (ki == 0) { pi_ = 31; qi_ = q0; }
      else { pi_ = (ai_ < bi_) ? ai_ : bi_; qi_ = (ai_ < bi_) ? bi_ : ai_; }
      if (kj == 0) { pj_ = 31; qj_ = q0; }
      else { pj_ = (aj_ < bj_) ? aj_ : bj_; qj_ = (aj_ < bj_) ? bj_ : aj_; }
      double ci = (double)rcs[ki], si = (double)rss[ki];
      double cj = (double)rcs[kj], sj = (double)rss[kj];
      double m00 = A[pi_][pj_], m01 = A[pi_][qj_];
      double m10 = A[qi_][pj_], m11 = A[qi_][qj_];
      // row rotation (J_ki^T from left)
      double r00 = ci * m00 - si * m10, r01 = ci * m01 - si * m11;
      double r10 = si * m00 + ci * m10, r11 = si * m01 + ci * m11;
      // col rotation (J_kj from right)
      A[pi_][pj_] = cj * r00 - sj * r01;
      A[pi_][qj_] = sj * r00 + cj * r01;
      A[qi_][pj_] = cj * r10 - sj * r11;
      A[qi_][qj_] = sj * r10 + cj * r11;
      // V: col rotation only (rows pi_,qi_ x cols pj_,qj_), f32
      float cjf = rcs[kj], sjf = rss[kj];
      float v00 = V[pi_][pj_], v01 = V[pi_][qj_];
      float v10 = V[qi_][pj_], v11 = V[qi_][qj_];
      V[pi_][pj_] = cjf * v00 - sjf * v01;
      V[pi_][qj_] = sjf * v00 + cjf * v01;
      V[qi_][pj_] = cjf * v10 - sjf * v11;
      V[qi_][qj_] = sjf * v10 + cjf * v11;
      __syncthreads();  // B2: U writes -> next P reads

      // advance mod-31 counters
      ai_ = (ai_ == 30) ? 0 : ai_ + 1;
      bi_ = (bi_ == 30) ? 0 : bi_ + 1;
      aj_ = (aj_ == 30) ? 0 : aj_ + 1;
      bj_ = (bj_ == 30) ? 0 : bj_ + 1;
      ma = (ma == 30) ? 0 : ma + 1;
      mb = (mb == 30) ? 0 : mb + 1;
      q0 = (q0 == 30) ? 0 : q0 + 1;
    }
  }
  __syncthreads();

  if (t == 0) {
    bool used[32];
    for (int i = 0; i < 32; ++i) used[i] = false;
    for (int j = 0; j < 3; ++j) {
      int best = 0; double bv = -1e300;
      for (int i = 0; i < 32; ++i)
        if (!used[i] && A[i][i] > bv) { bv = A[i][i]; best = i; }
      used[best] = true;
      sel[j] = best;
      int m = 0; float mv = fabsf(V[0][best]);
      for (int i = 1; i < 32; ++i) {
        float av = fabsf(V[i][best]);
        if (av > mv) { mv = av; m = i; }
      }
      ssign[j] = (V[m][best] < 0.0f) ? -1.0 : 1.0;
    }
  }
  __syncthreads();
  const float adj[3] = {SIGN0, SIGN1, SIGN2};
  if (t < 32) {
    for (int j = 0; j < 3; ++j)
      V3[j * 32 + t] = (float)ssign[j] * V[t][sel[j]] * adj[j];
  }
}

// Pass 4: out[a, j] = sum_k F[a,k] * V3[j,k]
__global__ __launch_bounds__(256) void proj_kernel(const float* __restrict__ F,
                                                   const float* __restrict__ V3,
                                                   float* __restrict__ out, int n) {
  __shared__ float v[96];
  if (threadIdx.x < 96) v[threadIdx.x] = V3[threadIdx.x];
  __syncthreads();
  int a = blockIdx.x * blockDim.x + threadIdx.x;
  if (a >= n) return;
  const float4* rowp = (const float4*)(F + (size_t)a * 32);
  float s0 = 0.f, s1 = 0.f, s2 = 0.f;
#pragma unroll
  for (int k4 = 0; k4 < 8; ++k4) {
    float4 f = rowp[k4];
    int k = k4 * 4;
    s0 += f.x * v[k] + f.y * v[k + 1] + f.z * v[k + 2] + f.w * v[k + 3];
    s1 += f.x * v[32 + k] + f.y * v[32 + k + 1] + f.z * v[32 + k + 2] + f.w * v[32 + k + 3];
    s2 += f.x * v[64 + k] + f.y * v[64 + k + 1] + f.z * v[64 + k + 2] + f.w * v[64 + k + 3];
  }
  out[3 * a + 0] = s0;
  out[3 * a + 1] = s1;
  out[3 * a + 2] = s2;
}

extern "C" void kernel_launch(void* const* d_in, const int* in_sizes, int n_in,
                              void* d_out, int out_size, void* d_ws, size_t ws_size,
                              hipStream_t stream) {
  const float* vec = (const float*)d_in[0];
  const int* atom = (const int*)d_in[1];
  int E = in_sizes[1];
  int n_atoms = out_size / 3;
  int nb = (n_atoms + 1023) >> 10;  // blocks for the coalesced scan (<=1024)

  char* ws = (char*)d_ws;
  auto nalign = [](size_t x) { return (x + 255) & ~(size_t)255; };

  size_t F_bytes = (size_t)n_atoms * MAX_K * sizeof(float);
  size_t sr_bytes = (size_t)E * sizeof(float);
  size_t i_bytes = (size_t)n_atoms * sizeof(int);

  size_t F_off = 0;
  size_t sr_off = nalign(F_off + F_bytes);
  size_t offs_off = nalign(sr_off + sr_bytes);
  size_t cur_off = nalign(offs_off + i_bytes);
  size_t cnt_off = nalign(cur_off + i_bytes);
  size_t G_off = nalign(cnt_off + i_bytes);
  size_t S_off = nalign(G_off + 1024 * sizeof(double));
  size_t bs_off = nalign(S_off + 32 * sizeof(double));
  size_t bb_off = nalign(bs_off + 1024 * sizeof(int));
  size_t V3_off = nalign(bb_off + 1024 * sizeof(int));
  size_t total = nalign(V3_off + 96 * sizeof(float));

  float* F = (float*)(ws + F_off);
  double* G = (double*)(ws + G_off);
  double* S = (double*)(ws + S_off);
  float* V3 = (float*)(ws + V3_off);

  // r_all aliases F's buffer (E*4B == n_atoms*32*4B); F written only by
  // build_kernel, after scatter8 has fully consumed r_all.
  float* r_all = F;

  if (ws_size >= total && sr_bytes <= F_bytes) {
    float* sr = (float*)(ws + sr_off);
    int* offset = (int*)(ws + offs_off);
    int* cursor = (int*)(ws + cur_off);
    int* count = (int*)(ws + cnt_off);
    int* bsum = (int*)(ws + bs_off);
    int* bbase = (int*)(ws + bb_off);
    // zero count + G + S (contiguous region)
    hipMemsetAsync(ws + cnt_off, 0, S_off + 32 * sizeof(double) - cnt_off, stream);
    r_hist_kernel<<<(E + 255) / 256, 256, 0, stream>>>(vec, atom, r_all, count, E);
    bsum_kernel<<<nb, 1024, 0, stream>>>(count, bsum, n_atoms);
    bscan_kernel<<<1, 1024, 0, stream>>>(bsum, bbase, nb);
    apply_kernel<<<nb, 1024, 0, stream>>>(count, bbase, offset, cursor, n_atoms);
    int nbpg = 512;  // blocks per group; grid = 8 * nbpg
    scatter8_kernel<<<8 * nbpg, 256, 0, stream>>>(r_all, atom, cursor, sr, E, n_atoms, nbpg);
    build_kernel<<<(n_atoms + 255) / 256, 256, 0, stream>>>(sr, offset, count, F, n_atoms);
    gram_kernel<<<1024, 256, 0, stream>>>(F, n_atoms, G, S);
    eig_kernel<<<1, 256, 0, stream>>>(G, S, V3, n_atoms);
    proj_kernel<<<(n_atoms + 255) / 256, 256, 0, stream>>>(F, V3, (float*)d_out, n_atoms);
  } else {
    hipMemsetAsync(ws, 0, F_bytes, stream);
    hipMemsetAsync(ws + cnt_off, 0, S_off + 32 * sizeof(double) - cnt_off, stream);
    edge_kernel<<<(E + 255) / 256, 256, 0, stream>>>(vec, atom, F, E);
    gram_kernel<<<1024, 256, 0, stream>>>(F, n_atoms, G, S);
    eig_kernel<<<1, 256, 0, stream>>>(G, S, V3, n_atoms);
    proj_kernel<<<(n_atoms + 255) / 256, 256, 0, stream>>>(F, V3, (float*)d_out, n_atoms);
  }
}